// Round 3
// baseline (2413.674 us; speedup 1.0000x reference)
//
#include <hip/hip_runtime.h>
#include <hip/hip_bf16.h>

#define NN 50000          // nodes
#define NE 800000         // edges
#define NR 3              // relations
#define NG 500            // graphs
#define NB (NN * NR)      // (dst, rel) buckets = 150000
#define NCLS 10
#define CHUNK 2048        // scan elements per block
#define NBLK ((NB + CHUNK - 1) / CHUNK)   // 74

typedef __hip_bfloat16 bf16;

static __device__ __forceinline__ float b2f(bf16 x) { return __bfloat162float(x); }
static __device__ __forceinline__ bf16  f2b(float x) { return __float2bfloat16(x); }

// ---------------- zero words (instead of hipMemsetAsync: graph-capture-safe)
__global__ __launch_bounds__(256) void zero_u32(unsigned* __restrict__ p, long n) {
    long i = (long)blockIdx.x * 256 + threadIdx.x;
    if (i < n) p[i] = 0u;
}

// ---------------- per-(dst,rel) edge counts
__global__ __launch_bounds__(256) void count_edges(const int* __restrict__ ei,
                                                   const int* __restrict__ et,
                                                   int* __restrict__ cnt) {
    int e = blockIdx.x * 256 + threadIdx.x;
    if (e >= NE) return;
    atomicAdd(&cnt[ei[NE + e] * NR + et[e]], 1);
}

// ---------------- counting-sort scan, phase A: per-block (2048-elem) totals
__global__ __launch_bounds__(256) void scan_block_sums(const int* __restrict__ cnt,
                                                       int* __restrict__ bsum) {
    __shared__ int sm[256];
    int b = blockIdx.x, t = threadIdx.x;
    int base = b * CHUNK + t * 8, s = 0;
#pragma unroll
    for (int j = 0; j < 8; ++j) { int i = base + j; if (i < NB) s += cnt[i]; }
    sm[t] = s; __syncthreads();
    for (int st = 128; st; st >>= 1) { if (t < st) sm[t] += sm[t + st]; __syncthreads(); }
    if (!t) bsum[b] = sm[0];
}

// ---------------- phase B: exclusive scan of the 74 block sums
__global__ void scan_base(const int* __restrict__ bsum, int* __restrict__ bbase,
                          int* __restrict__ off) {
    if (threadIdx.x == 0 && blockIdx.x == 0) {
        int run = 0;
        for (int i = 0; i < NBLK; ++i) { bbase[i] = run; run += bsum[i]; }
        off[NB] = run;   // == NE
    }
}

// ---------------- phase C: in-block exclusive scan + base -> off[], cursor[]
__global__ __launch_bounds__(256) void scan_write(const int* __restrict__ cnt,
                                                  const int* __restrict__ bbase,
                                                  int* __restrict__ off,
                                                  int* __restrict__ cursor) {
    int b = blockIdx.x, t = threadIdx.x;
    int base = b * CHUNK + t * 8;
    int v[8], ts = 0;
#pragma unroll
    for (int j = 0; j < 8; ++j) { int i = base + j; v[j] = (i < NB) ? cnt[i] : 0; ts += v[j]; }
    int lane = t & 63, wv = t >> 6;
    int incl = ts;
    for (int d = 1; d < 64; d <<= 1) {
        int o = __shfl_up(incl, d, 64);
        if (lane >= d) incl += o;
    }
    __shared__ int wsum[4];
    if (lane == 63) wsum[wv] = incl;
    __syncthreads();
    int wbase = 0;
    for (int w = 0; w < wv; ++w) wbase += wsum[w];
    int run = bbase[b] + wbase + incl - ts;   // exclusive base for this thread's 8 elems
#pragma unroll
    for (int j = 0; j < 8; ++j) {
        int i = base + j;
        if (i < NB) { off[i] = run; cursor[i] = run; }
        run += v[j];
    }
}

// ---------------- bucket-sort edge src indices (CSR payload)
__global__ __launch_bounds__(256) void scatter_edges(const int* __restrict__ ei,
                                                     const int* __restrict__ et,
                                                     int* __restrict__ cursor,
                                                     int* __restrict__ eidx) {
    int e = blockIdx.x * 256 + threadIdx.x;
    if (e >= NE) return;
    int b = ei[NE + e] * NR + et[e];
    int pos = atomicAdd(&cursor[b], 1);
    eidx[pos] = ei[e];
}

// ---------------- layer-1 GEMM with fused embedding gather (all f32 inputs):
// A[m][k] = concat(se[s[m]], ce[c[m]], pe[p[m]])[k], K=384; C = A @ B (K x 256) -> bf16
__global__ __launch_bounds__(256) void gemm_l1(const int* __restrict__ s,
                                               const int* __restrict__ c,
                                               const int* __restrict__ p,
                                               const float* __restrict__ se,
                                               const float* __restrict__ ce,
                                               const float* __restrict__ pe,
                                               const float* __restrict__ B,
                                               bf16* __restrict__ C) {
    __shared__ float As[16][132];
    __shared__ float Bs[16][132];
    const int t = threadIdx.x, tx = t & 15, ty = t >> 4;
    const int row0 = blockIdx.y * 128, col0 = blockIdx.x * 128;
    float acc[8][8] = {};
    for (int k0 = 0; k0 < 384; k0 += 16) {
#pragma unroll
        for (int i = 0; i < 8; ++i) {
            int e = t + 256 * i;
            int m = e >> 4, kk = e & 15, gm = row0 + m, k = k0 + kk;
            float v = 0.f;
            if (gm < NN) {
                if (k < 128)      v = se[s[gm] * 128 + k];
                else if (k < 256) v = ce[c[gm] * 128 + k - 128];
                else              v = pe[p[gm] * 128 + k - 256];
            }
            As[kk][m] = v;
        }
#pragma unroll
        for (int i = 0; i < 8; ++i) {
            int e = t + 256 * i;
            int kk = e >> 7, n = e & 127;
            Bs[kk][n] = B[(size_t)(k0 + kk) * 256 + col0 + n];
        }
        __syncthreads();
#pragma unroll
        for (int kk = 0; kk < 16; ++kk) {
            float a[8], bb[8];
            *(float4*)&a[0]  = *(const float4*)&As[kk][ty * 8];
            *(float4*)&a[4]  = *(const float4*)&As[kk][ty * 8 + 4];
            *(float4*)&bb[0] = *(const float4*)&Bs[kk][tx * 8];
            *(float4*)&bb[4] = *(const float4*)&Bs[kk][tx * 8 + 4];
#pragma unroll
            for (int i = 0; i < 8; ++i)
#pragma unroll
                for (int j = 0; j < 8; ++j) acc[i][j] += a[i] * bb[j];
        }
        __syncthreads();
    }
#pragma unroll
    for (int i = 0; i < 8; ++i) {
        int gm = row0 + ty * 8 + i;
        if (gm < NN) {
#pragma unroll
            for (int j = 0; j < 8; j += 2) {
                __hip_bfloat162 pr;
                pr.x = f2b(acc[i][j]); pr.y = f2b(acc[i][j + 1]);
                *(__hip_bfloat162*)&C[(size_t)gm * 256 + col0 + tx * 8 + j] = pr;
            }
        }
    }
}

// ---------------- layer-2 GEMM: A bf16 (N x 256) @ B f32 (256 x 256) -> bf16
__global__ __launch_bounds__(256) void gemm_h(const bf16* __restrict__ A,
                                              const float* __restrict__ B,
                                              bf16* __restrict__ C) {
    __shared__ float As[16][132];
    __shared__ float Bs[16][132];
    const int t = threadIdx.x, tx = t & 15, ty = t >> 4;
    const int row0 = blockIdx.y * 128, col0 = blockIdx.x * 128;
    float acc[8][8] = {};
    for (int k0 = 0; k0 < 256; k0 += 16) {
#pragma unroll
        for (int i = 0; i < 8; ++i) {
            int e = t + 256 * i;
            int m = e >> 4, kk = e & 15, gm = row0 + m;
            As[kk][m] = (gm < NN) ? b2f(A[(size_t)gm * 256 + k0 + kk]) : 0.f;
        }
#pragma unroll
        for (int i = 0; i < 8; ++i) {
            int e = t + 256 * i;
            int kk = e >> 7, n = e & 127;
            Bs[kk][n] = B[(size_t)(k0 + kk) * 256 + col0 + n];
        }
        __syncthreads();
#pragma unroll
        for (int kk = 0; kk < 16; ++kk) {
            float a[8], bb[8];
            *(float4*)&a[0]  = *(const float4*)&As[kk][ty * 8];
            *(float4*)&a[4]  = *(const float4*)&As[kk][ty * 8 + 4];
            *(float4*)&bb[0] = *(const float4*)&Bs[kk][tx * 8];
            *(float4*)&bb[4] = *(const float4*)&Bs[kk][tx * 8 + 4];
#pragma unroll
            for (int i = 0; i < 8; ++i)
#pragma unroll
                for (int j = 0; j < 8; ++j) acc[i][j] += a[i] * bb[j];
        }
        __syncthreads();
    }
#pragma unroll
    for (int i = 0; i < 8; ++i) {
        int gm = row0 + ty * 8 + i;
        if (gm < NN) {
#pragma unroll
            for (int j = 0; j < 8; j += 2) {
                __hip_bfloat162 pr;
                pr.x = f2b(acc[i][j]); pr.y = f2b(acc[i][j + 1]);
                *(__hip_bfloat162*)&C[(size_t)gm * 256 + col0 + tx * 8 + j] = pr;
            }
        }
    }
}

// ---------------- segmented mean per (dst, r): H[dst] += mean_{src in bucket} Y[src]
__global__ __launch_bounds__(256) void agg_mean(const int* __restrict__ off,
                                                const int* __restrict__ eidx,
                                                const bf16* __restrict__ Y,
                                                bf16* __restrict__ H, int r) {
    int dst = blockIdx.x, t = threadIdx.x;
    int b = dst * NR + r;
    int lo = off[b], hi = off[b + 1];
    if (lo == hi) return;                       // empty bucket contributes 0 (matches ref)
    float acc = 0.f;
    for (int j = lo; j < hi; ++j) {
        int src = eidx[j];
        acc += b2f(Y[(size_t)src * 256 + t]);   // coalesced 512B row read
    }
    float inv = 1.0f / (float)(hi - lo);
    size_t o = (size_t)dst * 256 + t;
    H[o] = f2b(b2f(H[o]) + acc * inv);
}

// ---------------- H = relu(H + Yroot + bias)   (bias is f32)
__global__ __launch_bounds__(256) void epilogue(bf16* __restrict__ H,
                                                const bf16* __restrict__ Y,
                                                const float* __restrict__ bias) {
    long idx = (long)blockIdx.x * 256 + threadIdx.x;
    if (idx >= (long)NN * 256) return;
    int d = idx & 255;
    float v = b2f(H[idx]) + b2f(Y[idx]) + bias[d];
    H[idx] = f2b(fmaxf(v, 0.f));
}

// ---------------- per-graph pooling (f32 atomics)
__global__ __launch_bounds__(256) void pool_scatter(const int* __restrict__ batch,
                                                    const bf16* __restrict__ H,
                                                    float* __restrict__ pool,
                                                    float* __restrict__ gcnt) {
    long idx = (long)blockIdx.x * 256 + threadIdx.x;
    if (idx >= (long)NN * 256) return;
    int n = (int)(idx >> 8), d = (int)(idx & 255);
    int g = batch[n];
    atomicAdd(&pool[(size_t)g * 256 + d], b2f(H[idx]));
    if (d == 0) atomicAdd(&gcnt[g], 1.0f);
}

// ---------------- head: out[g][c] = (pool[g]/cnt[g]) @ lin_w + lin_b  (f32 out)
__global__ __launch_bounds__(256) void final_head(const float* __restrict__ pool,
                                                  const float* __restrict__ gcnt,
                                                  const float* __restrict__ lin_w,
                                                  const float* __restrict__ lin_b,
                                                  float* __restrict__ out) {
    __shared__ float sm[256];
    int g = blockIdx.x, t = threadIdx.x;
    float inv = 1.0f / fmaxf(gcnt[g], 1.0f);
    sm[t] = pool[(size_t)g * 256 + t] * inv;
    __syncthreads();
    if (t < NCLS) {
        float s = lin_b[t];
        for (int d = 0; d < 256; ++d) s += sm[d] * lin_w[d * NCLS + t];
        out[g * NCLS + t] = s;
    }
}

extern "C" void kernel_launch(void* const* d_in, const int* in_sizes, int n_in,
                              void* d_out, int out_size, void* d_ws, size_t ws_size,
                              hipStream_t stream) {
    const int*   s_idx = (const int*)d_in[0];
    const int*   c_idx = (const int*)d_in[1];
    const int*   p_idx = (const int*)d_in[2];
    const int*   ei    = (const int*)d_in[3];   // (2, NE)
    const int*   et    = (const int*)d_in[4];
    const int*   batch = (const int*)d_in[5];
    const float* se    = (const float*)d_in[6];
    const float* ce    = (const float*)d_in[7];
    const float* pe    = (const float*)d_in[8];
    const float* W1    = (const float*)d_in[9];   // (3, 384, 256)
    const float* root1 = (const float*)d_in[10];  // (384, 256)
    const float* b1    = (const float*)d_in[11];
    const float* W2    = (const float*)d_in[12];  // (3, 256, 256)
    const float* root2 = (const float*)d_in[13];  // (256, 256)
    const float* b2    = (const float*)d_in[14];
    const float* lin_w = (const float*)d_in[15];
    const float* lin_b = (const float*)d_in[16];
    float* out = (float*)d_out;

    // ---- workspace carve-up (~82.5 MB total; all offsets 16B-aligned)
    char* w = (char*)d_ws;
    size_t o = 0;
    auto alloc = [&](size_t bytes) -> void* {
        o = (o + 15) & ~(size_t)15;
        void* ptr = w + o;
        o += bytes;
        return ptr;
    };
    bf16* Yr     = (bf16*)alloc((size_t)NN * 256 * 2);   // per-relation GEMM output (reused 8x)
    bf16* h1     = (bf16*)alloc((size_t)NN * 256 * 2);
    bf16* h2     = (bf16*)alloc((size_t)NN * 256 * 2);
    int*  eidx   = (int*) alloc((size_t)NE * 4);
    int*  cnt    = (int*) alloc((size_t)NB * 4);
    int*  off    = (int*) alloc((size_t)(NB + 1) * 4);
    int*  cursor = (int*) alloc((size_t)NB * 4);
    int*  bsum   = (int*) alloc((size_t)NBLK * 4);
    int*  bbase  = (int*) alloc((size_t)NBLK * 4);
    float* pool  = (float*)alloc((size_t)NG * 256 * 4);
    float* gcnt  = (float*)alloc((size_t)NG * 4);
    (void)ws_size;

    const long HW = (long)NN * 128;     // h buffer size in u32 words (bf16 x2)

    // ---- CSR build: count -> scan -> scatter
    zero_u32<<<(NB + 255) / 256, 256, 0, stream>>>((unsigned*)cnt, NB);
    count_edges<<<(NE + 255) / 256, 256, 0, stream>>>(ei, et, cnt);
    scan_block_sums<<<NBLK, 256, 0, stream>>>(cnt, bsum);
    scan_base<<<1, 64, 0, stream>>>(bsum, bbase, off);
    scan_write<<<NBLK, 256, 0, stream>>>(cnt, bbase, off, cursor);
    scatter_edges<<<(NE + 255) / 256, 256, 0, stream>>>(ei, et, cursor, eidx);

    dim3 ggrid(2, (NN + 127) / 128);    // 256 cols / 128, 391 row-tiles

    // ---- layer 1 (A = gathered embeddings, K=384)
    zero_u32<<<(int)((HW + 255) / 256), 256, 0, stream>>>((unsigned*)h1, HW);
    for (int r = 0; r < NR; ++r) {
        gemm_l1<<<ggrid, 256, 0, stream>>>(s_idx, c_idx, p_idx, se, ce, pe,
                                           W1 + (size_t)r * 384 * 256, Yr);
        agg_mean<<<NN, 256, 0, stream>>>(off, eidx, Yr, h1, r);
    }
    gemm_l1<<<ggrid, 256, 0, stream>>>(s_idx, c_idx, p_idx, se, ce, pe, root1, Yr);
    epilogue<<<(int)(((long)NN * 256 + 255) / 256), 256, 0, stream>>>(h1, Yr, b1);

    // ---- layer 2 (A = h1, K=256)
    zero_u32<<<(int)((HW + 255) / 256), 256, 0, stream>>>((unsigned*)h2, HW);
    for (int r = 0; r < NR; ++r) {
        gemm_h<<<ggrid, 256, 0, stream>>>(h1, W2 + (size_t)r * 256 * 256, Yr);
        agg_mean<<<NN, 256, 0, stream>>>(off, eidx, Yr, h2, r);
    }
    gemm_h<<<ggrid, 256, 0, stream>>>(h1, root2, Yr);
    epilogue<<<(int)(((long)NN * 256 + 255) / 256), 256, 0, stream>>>(h2, Yr, b2);

    // ---- pool + head
    zero_u32<<<(NG * 256 + NG + 255) / 256, 256, 0, stream>>>((unsigned*)pool, NG * 256 + NG);
    pool_scatter<<<(int)(((long)NN * 256 + 255) / 256), 256, 0, stream>>>(batch, h2, pool, gcnt);
    final_head<<<NG, 256, 0, stream>>>(pool, gcnt, lin_w, lin_b, out);
}

// Round 4
// 797.766 us; speedup vs baseline: 3.0255x; 3.0255x over previous
//
#include <hip/hip_runtime.h>
#include <hip/hip_bf16.h>

#define NN 50000          // nodes
#define NE 800000         // edges
#define NR 3              // relations
#define NG 500            // graphs
#define NB (NN * NR)      // (dst, rel) buckets = 150000
#define NCLS 10
#define CHUNK 2048        // scan elements per block
#define NBLK ((NB + CHUNK - 1) / CHUNK)   // 74

typedef __hip_bfloat16 bf16;
typedef __attribute__((ext_vector_type(8))) short short8;   // bf16x8 MFMA frag (guide §3)
typedef __attribute__((ext_vector_type(4))) float floatx4;  // MFMA accumulator

static __device__ __forceinline__ float b2f(bf16 x) { return __bfloat162float(x); }
static __device__ __forceinline__ bf16  f2b(float x) { return __float2bfloat16(x); }

// ---------------- zero words (graph-capture-safe)
__global__ __launch_bounds__(256) void zero_u32(unsigned* __restrict__ p, long n) {
    long i = (long)blockIdx.x * 256 + threadIdx.x;
    if (i < n) p[i] = 0u;
}

// ---------------- per-(dst,rel) edge counts
__global__ __launch_bounds__(256) void count_edges(const int* __restrict__ ei,
                                                   const int* __restrict__ et,
                                                   int* __restrict__ cnt) {
    int e = blockIdx.x * 256 + threadIdx.x;
    if (e >= NE) return;
    atomicAdd(&cnt[ei[NE + e] * NR + et[e]], 1);
}

// ---------------- counting-sort scan, phase A: per-block (2048-elem) totals
__global__ __launch_bounds__(256) void scan_block_sums(const int* __restrict__ cnt,
                                                       int* __restrict__ bsum) {
    __shared__ int sm[256];
    int b = blockIdx.x, t = threadIdx.x;
    int base = b * CHUNK + t * 8, s = 0;
#pragma unroll
    for (int j = 0; j < 8; ++j) { int i = base + j; if (i < NB) s += cnt[i]; }
    sm[t] = s; __syncthreads();
    for (int st = 128; st; st >>= 1) { if (t < st) sm[t] += sm[t + st]; __syncthreads(); }
    if (!t) bsum[b] = sm[0];
}

// ---------------- phase B: exclusive scan of the 74 block sums
__global__ void scan_base(const int* __restrict__ bsum, int* __restrict__ bbase,
                          int* __restrict__ off) {
    if (threadIdx.x == 0 && blockIdx.x == 0) {
        int run = 0;
        for (int i = 0; i < NBLK; ++i) { bbase[i] = run; run += bsum[i]; }
        off[NB] = run;   // == NE
    }
}

// ---------------- phase C: in-block exclusive scan + base -> off[], cursor[]
__global__ __launch_bounds__(256) void scan_write(const int* __restrict__ cnt,
                                                  const int* __restrict__ bbase,
                                                  int* __restrict__ off,
                                                  int* __restrict__ cursor) {
    int b = blockIdx.x, t = threadIdx.x;
    int base = b * CHUNK + t * 8;
    int v[8], ts = 0;
#pragma unroll
    for (int j = 0; j < 8; ++j) { int i = base + j; v[j] = (i < NB) ? cnt[i] : 0; ts += v[j]; }
    int lane = t & 63, wv = t >> 6;
    int incl = ts;
    for (int d = 1; d < 64; d <<= 1) {
        int o = __shfl_up(incl, d, 64);
        if (lane >= d) incl += o;
    }
    __shared__ int wsum[4];
    if (lane == 63) wsum[wv] = incl;
    __syncthreads();
    int wbase = 0;
    for (int w = 0; w < wv; ++w) wbase += wsum[w];
    int run = bbase[b] + wbase + incl - ts;
#pragma unroll
    for (int j = 0; j < 8; ++j) {
        int i = base + j;
        if (i < NB) { off[i] = run; cursor[i] = run; }
        run += v[j];
    }
}

// ---------------- bucket-sort edge src indices (CSR payload)
__global__ __launch_bounds__(256) void scatter_edges(const int* __restrict__ ei,
                                                     const int* __restrict__ et,
                                                     int* __restrict__ cursor,
                                                     int* __restrict__ eidx) {
    int e = blockIdx.x * 256 + threadIdx.x;
    if (e >= NE) return;
    int b = ei[NE + e] * NR + et[e];
    int pos = atomicAdd(&cursor[b], 1);
    eidx[pos] = ei[e];
}

// ---------------- layer-1 tables: tab[r][row][n] for r in 0..3 (3 rels + root)
// rows: 0..7 = se @ Wseg0, 8..15 = ce @ Wseg1, 16..143 = pe @ Wseg2   (K=128 each)
__global__ __launch_bounds__(256) void tab_gemm(const float* __restrict__ se,
                                                const float* __restrict__ ce,
                                                const float* __restrict__ pe,
                                                const float* __restrict__ W1,
                                                const float* __restrict__ root1,
                                                float* __restrict__ tab) {
    int bid = blockIdx.x;              // 4*144 blocks
    int r = bid / 144, row = bid % 144;
    int t = threadIdx.x;               // output column 0..255
    const float* A; int segk;
    if (row < 8)       { A = se + row * 128;        segk = 0; }
    else if (row < 16) { A = ce + (row - 8) * 128;  segk = 128; }
    else               { A = pe + (row - 16) * 128; segk = 256; }
    const float* W = (r < 3) ? (W1 + (size_t)r * 384 * 256) : root1;
    float acc = 0.f;
    for (int k = 0; k < 128; ++k)
        acc += A[k] * W[(size_t)(segk + k) * 256 + t];
    tab[((size_t)r * 144 + row) * 256 + t] = acc;
}

// ---------------- fused layer 1: h1[dst] = relu( sum_r mean_{src in bucket(dst,r)}
//                  (tab[r][s[src]] + tab[r][8+c[src]] + tab[r][16+p[src]])  + tab[3][...dst...] + b1 )
__global__ __launch_bounds__(256) void l1_fused(const int* __restrict__ off,
                                                const int* __restrict__ eidx,
                                                const int* __restrict__ s,
                                                const int* __restrict__ c,
                                                const int* __restrict__ p,
                                                const float* __restrict__ tab,
                                                const float* __restrict__ b1,
                                                bf16* __restrict__ h1) {
    int dst = blockIdx.x, t = threadIdx.x;
    float acc = 0.f;
    for (int r = 0; r < NR; ++r) {
        int lo = off[dst * NR + r], hi = off[dst * NR + r + 1];
        if (hi <= lo) continue;                       // empty bucket contributes 0 (matches ref)
        const float* tr = tab + (size_t)r * 144 * 256;
        float sum = 0.f;
        for (int j = lo; j < hi; ++j) {
            int src = eidx[j];
            sum += tr[(s[src]) * 256 + t] + tr[(8 + c[src]) * 256 + t] + tr[(16 + p[src]) * 256 + t];
        }
        acc += sum / (float)(hi - lo);
    }
    const float* tr = tab + (size_t)3 * 144 * 256;    // root
    acc += tr[(s[dst]) * 256 + t] + tr[(8 + c[dst]) * 256 + t] + tr[(16 + p[dst]) * 256 + t] + b1[t];
    h1[(size_t)dst * 256 + t] = f2b(fmaxf(acc, 0.f));
}

// ---------------- W2 -> bf16, transposed: Wt[r][n][k] = W2[r][k][n] (r=3 -> root2)
__global__ __launch_bounds__(256) void conv_w2t(const float* __restrict__ W2,
                                                const float* __restrict__ root2,
                                                bf16* __restrict__ Wt) {
    int idx = blockIdx.x * 256 + threadIdx.x;   // 4*256*256
    if (idx >= 4 * 256 * 256) return;
    int r = idx >> 16, rem = idx & 65535, n = rem >> 8, k = rem & 255;
    float v = (r < 3) ? W2[((size_t)r * 256 + k) * 256 + n] : root2[(size_t)k * 256 + n];
    Wt[idx] = f2b(v);
}

// ---------------- MFMA bf16 GEMM: C[M][256] = A[M][256] @ Bt^T  (Bt is [n][k])
// 128x128 tile, 4 waves, each wave a 64x64 quadrant = 4x4 grid of 16x16x32 MFMAs.
// root_mode: C = relu(acc + Hacc + bias) else C = acc.  bf16 out.
__global__ __launch_bounds__(256) void gemm_mfma(const bf16* __restrict__ A,
                                                 const bf16* __restrict__ Bt,
                                                 const bf16* __restrict__ Hacc,
                                                 const float* __restrict__ bias,
                                                 bf16* __restrict__ C,
                                                 int root_mode) {
    // LDS row stride 40 shorts (80 B): 16B-aligned ds_read_b128, 2-way-conflict-free
    __shared__ short As[128 * 40];
    __shared__ short Bs[128 * 40];
    const int t = threadIdx.x;
    const int wave = t >> 6, lane = t & 63;
    const int quad = lane >> 4, l16 = lane & 15;
    const int mq = (wave & 1) * 64, nq = (wave >> 1) * 64;
    const int row0 = blockIdx.y * 128, col0 = blockIdx.x * 128;
    const int sm = t >> 2;            // staging row 0..63
    const int sp = (t & 3) * 8;       // staging k-offset {0,8,16,24}

    floatx4 acc[4][4] = {};

    for (int k0 = 0; k0 < 256; k0 += 32) {
#pragma unroll
        for (int h = 0; h < 2; ++h) {
            int m = sm + h * 64;
            int gm = row0 + m;
            short8 av = {};
            if (gm < NN) av = *(const short8*)(A + (size_t)gm * 256 + k0 + sp);
            *(short8*)&As[m * 40 + sp] = av;
            short8 bv = *(const short8*)(Bt + (size_t)(col0 + m) * 256 + k0 + sp);
            *(short8*)&Bs[m * 40 + sp] = bv;
        }
        __syncthreads();
        short8 af[4], bfr[4];
#pragma unroll
        for (int i = 0; i < 4; ++i)
            af[i] = *(const short8*)&As[(mq + i * 16 + l16) * 40 + quad * 8];
#pragma unroll
        for (int i = 0; i < 4; ++i)
            bfr[i] = *(const short8*)&Bs[(nq + i * 16 + l16) * 40 + quad * 8];
#pragma unroll
        for (int mi = 0; mi < 4; ++mi)
#pragma unroll
            for (int ni = 0; ni < 4; ++ni)
                acc[mi][ni] = __builtin_amdgcn_mfma_f32_16x16x32_bf16(
                    af[mi], bfr[ni], acc[mi][ni], 0, 0, 0);
        __syncthreads();
    }

    // C/D layout: col = lane&15, row = quad*4 + reg   [guide §3, m89/m91-verified]
#pragma unroll
    for (int mi = 0; mi < 4; ++mi) {
#pragma unroll
        for (int ni = 0; ni < 4; ++ni) {
            int n = col0 + nq + ni * 16 + l16;
#pragma unroll
            for (int i = 0; i < 4; ++i) {
                int gm = row0 + mq + mi * 16 + quad * 4 + i;
                if (gm < NN) {
                    float v = acc[mi][ni][i];
                    if (root_mode) {
                        v += b2f(Hacc[(size_t)gm * 256 + n]) + bias[n];
                        v = fmaxf(v, 0.f);
                    }
                    C[(size_t)gm * 256 + n] = f2b(v);
                }
            }
        }
    }
}

// ---------------- segmented mean per (dst, r): H[dst] += mean_{src in bucket} Y[src]
// 128 threads, bf16x2 per thread (256B/wave coalesced reads)
__global__ __launch_bounds__(128) void agg_mean(const int* __restrict__ off,
                                                const int* __restrict__ eidx,
                                                const bf16* __restrict__ Y,
                                                bf16* __restrict__ H, int r) {
    int dst = blockIdx.x, t = threadIdx.x;
    int b = dst * NR + r;
    int lo = off[b], hi = off[b + 1];
    if (lo == hi) return;
    float ax = 0.f, ay = 0.f;
    for (int j = lo; j < hi; ++j) {
        int src = eidx[j];
        __hip_bfloat162 v = *(const __hip_bfloat162*)(Y + (size_t)src * 256 + t * 2);
        ax += b2f(v.x); ay += b2f(v.y);
    }
    float inv = 1.0f / (float)(hi - lo);
    size_t o = (size_t)dst * 256 + t * 2;
    __hip_bfloat162 hv = *(__hip_bfloat162*)(H + o);
    hv.x = f2b(b2f(hv.x) + ax * inv);
    hv.y = f2b(b2f(hv.y) + ay * inv);
    *(__hip_bfloat162*)(H + o) = hv;
}

// ---------------- per-graph pooling (f32 atomics)
__global__ __launch_bounds__(256) void pool_scatter(const int* __restrict__ batch,
                                                    const bf16* __restrict__ H,
                                                    float* __restrict__ pool,
                                                    float* __restrict__ gcnt) {
    long idx = (long)blockIdx.x * 256 + threadIdx.x;
    if (idx >= (long)NN * 256) return;
    int n = (int)(idx >> 8), d = (int)(idx & 255);
    int g = batch[n];
    atomicAdd(&pool[(size_t)g * 256 + d], b2f(H[idx]));
    if (d == 0) atomicAdd(&gcnt[g], 1.0f);
}

// ---------------- head: out[g][c] = (pool[g]/cnt[g]) @ lin_w + lin_b  (f32 out)
__global__ __launch_bounds__(256) void final_head(const float* __restrict__ pool,
                                                  const float* __restrict__ gcnt,
                                                  const float* __restrict__ lin_w,
                                                  const float* __restrict__ lin_b,
                                                  float* __restrict__ out) {
    __shared__ float sm[256];
    int g = blockIdx.x, t = threadIdx.x;
    float inv = 1.0f / fmaxf(gcnt[g], 1.0f);
    sm[t] = pool[(size_t)g * 256 + t] * inv;
    __syncthreads();
    if (t < NCLS) {
        float s = lin_b[t];
        for (int d = 0; d < 256; ++d) s += sm[d] * lin_w[d * NCLS + t];
        out[g * NCLS + t] = s;
    }
}

extern "C" void kernel_launch(void* const* d_in, const int* in_sizes, int n_in,
                              void* d_out, int out_size, void* d_ws, size_t ws_size,
                              hipStream_t stream) {
    const int*   s_idx = (const int*)d_in[0];
    const int*   c_idx = (const int*)d_in[1];
    const int*   p_idx = (const int*)d_in[2];
    const int*   ei    = (const int*)d_in[3];   // (2, NE)
    const int*   et    = (const int*)d_in[4];
    const int*   batch = (const int*)d_in[5];
    const float* se    = (const float*)d_in[6];
    const float* ce    = (const float*)d_in[7];
    const float* pe    = (const float*)d_in[8];
    const float* W1    = (const float*)d_in[9];   // (3, 384, 256)
    const float* root1 = (const float*)d_in[10];  // (384, 256)
    const float* b1    = (const float*)d_in[11];
    const float* W2    = (const float*)d_in[12];  // (3, 256, 256)
    const float* root2 = (const float*)d_in[13];  // (256, 256)
    const float* b2    = (const float*)d_in[14];
    const float* lin_w = (const float*)d_in[15];
    const float* lin_b = (const float*)d_in[16];
    float* out = (float*)d_out;

    // ---- workspace carve-up (~83.4 MB total; 16B-aligned)
    char* w = (char*)d_ws;
    size_t o = 0;
    auto alloc = [&](size_t bytes) -> void* {
        o = (o + 15) & ~(size_t)15;
        void* ptr = w + o;
        o += bytes;
        return ptr;
    };
    bf16*  Yr     = (bf16*) alloc((size_t)NN * 256 * 2);   // per-relation GEMM output
    bf16*  h1     = (bf16*) alloc((size_t)NN * 256 * 2);
    bf16*  h2     = (bf16*) alloc((size_t)NN * 256 * 2);
    int*   eidx   = (int*)  alloc((size_t)NE * 4);
    int*   cnt    = (int*)  alloc((size_t)NB * 4);
    int*   off    = (int*)  alloc((size_t)(NB + 1) * 4);
    int*   cursor = (int*)  alloc((size_t)NB * 4);
    int*   bsum   = (int*)  alloc((size_t)NBLK * 4);
    int*   bbase  = (int*)  alloc((size_t)NBLK * 4);
    float* tab    = (float*)alloc((size_t)4 * 144 * 256 * 4);
    bf16*  W2t    = (bf16*) alloc((size_t)4 * 256 * 256 * 2);
    float* pool   = (float*)alloc((size_t)NG * 256 * 4);
    float* gcnt   = (float*)alloc((size_t)NG * 4);
    (void)ws_size;

    const long HW = (long)NN * 128;     // h buffer in u32 words (bf16 x2)

    // ---- CSR build
    zero_u32<<<(NB + 255) / 256, 256, 0, stream>>>((unsigned*)cnt, NB);
    count_edges<<<(NE + 255) / 256, 256, 0, stream>>>(ei, et, cnt);
    scan_block_sums<<<NBLK, 256, 0, stream>>>(cnt, bsum);
    scan_base<<<1, 64, 0, stream>>>(bsum, bbase, off);
    scan_write<<<NBLK, 256, 0, stream>>>(cnt, bbase, off, cursor);
    scatter_edges<<<(NE + 255) / 256, 256, 0, stream>>>(ei, et, cursor, eidx);

    // ---- weight prep
    tab_gemm<<<4 * 144, 256, 0, stream>>>(se, ce, pe, W1, root1, tab);
    conv_w2t<<<(4 * 256 * 256 + 255) / 256, 256, 0, stream>>>(W2, root2, W2t);

    // ---- layer 1: fully fused (table gather + mean-agg + root + bias + relu)
    l1_fused<<<NN, 256, 0, stream>>>(off, eidx, s_idx, c_idx, p_idx, tab, b1, h1);

    // ---- layer 2: MFMA GEMM per relation + CSR mean-agg; root GEMM fuses epilogue
    zero_u32<<<(int)((HW + 255) / 256), 256, 0, stream>>>((unsigned*)h2, HW);
    dim3 ggrid(2, (NN + 127) / 128);
    for (int r = 0; r < NR; ++r) {
        gemm_mfma<<<ggrid, 256, 0, stream>>>(h1, W2t + (size_t)r * 256 * 256, h2, b2, Yr, 0);
        agg_mean<<<NN, 128, 0, stream>>>(off, eidx, Yr, h2, r);
    }
    gemm_mfma<<<ggrid, 256, 0, stream>>>(h1, W2t + (size_t)3 * 256 * 256, h2, b2, h2, 1);

    // ---- pool + head
    zero_u32<<<(NG * 256 + NG + 255) / 256, 256, 0, stream>>>((unsigned*)pool, NG * 256 + NG);
    pool_scatter<<<(int)(((long)NN * 256 + 255) / 256), 256, 0, stream>>>(batch, h2, pool, gcnt);
    final_head<<<NG, 256, 0, stream>>>(pool, gcnt, lin_w, lin_b, out);
}

// Round 5
// 538.250 us; speedup vs baseline: 4.4843x; 1.4821x over previous
//
#include <hip/hip_runtime.h>
#include <hip/hip_bf16.h>

#define NN 50000          // nodes
#define NE 800000         // edges
#define NR 3              // relations
#define NG 500            // graphs
#define NB (NN * NR)      // (dst, rel) buckets = 150000
#define NCLS 10
#define NCMB 8192         // 8 shapes * 8 colors * 128 positions
#define CHUNK 2048        // scan elements per block
#define NBLK ((NB + CHUNK - 1) / CHUNK)   // 74

typedef __hip_bfloat16 bf16;
typedef __attribute__((ext_vector_type(8))) short short8;   // bf16x8 MFMA frag
typedef __attribute__((ext_vector_type(4))) float floatx4;  // MFMA accumulator

static __device__ __forceinline__ float b2f(bf16 x) { return __bfloat162float(x); }
static __device__ __forceinline__ bf16  f2b(float x) { return __float2bfloat16(x); }
static __device__ __forceinline__ float bs2f(short x) {
    return __bfloat162float(*reinterpret_cast<const bf16*>(&x));
}
static __device__ __forceinline__ short f2bs(float x) {
    bf16 b = __float2bfloat16(x);
    return *reinterpret_cast<const short*>(&b);
}

// ---------------- zero words (graph-capture-safe)
__global__ __launch_bounds__(256) void zero_u32(unsigned* __restrict__ p, long n) {
    long i = (long)blockIdx.x * 256 + threadIdx.x;
    if (i < n) p[i] = 0u;
}

// ---------------- per-(dst,rel) edge counts
__global__ __launch_bounds__(256) void count_edges(const int* __restrict__ ei,
                                                   const int* __restrict__ et,
                                                   int* __restrict__ cnt) {
    int e = blockIdx.x * 256 + threadIdx.x;
    if (e >= NE) return;
    atomicAdd(&cnt[ei[NE + e] * NR + et[e]], 1);
}

// ---------------- counting-sort scan, phase A: per-block (2048-elem) totals
__global__ __launch_bounds__(256) void scan_block_sums(const int* __restrict__ cnt,
                                                       int* __restrict__ bsum) {
    __shared__ int sm[256];
    int b = blockIdx.x, t = threadIdx.x;
    int base = b * CHUNK + t * 8, s = 0;
#pragma unroll
    for (int j = 0; j < 8; ++j) { int i = base + j; if (i < NB) s += cnt[i]; }
    sm[t] = s; __syncthreads();
    for (int st = 128; st; st >>= 1) { if (t < st) sm[t] += sm[t + st]; __syncthreads(); }
    if (!t) bsum[b] = sm[0];
}

// ---------------- phase B: exclusive scan of the 74 block sums
__global__ void scan_base(const int* __restrict__ bsum, int* __restrict__ bbase,
                          int* __restrict__ off) {
    if (threadIdx.x == 0 && blockIdx.x == 0) {
        int run = 0;
        for (int i = 0; i < NBLK; ++i) { bbase[i] = run; run += bsum[i]; }
        off[NB] = run;   // == NE
    }
}

// ---------------- phase C: in-block exclusive scan + base -> off[], cursor[]
__global__ __launch_bounds__(256) void scan_write(const int* __restrict__ cnt,
                                                  const int* __restrict__ bbase,
                                                  int* __restrict__ off,
                                                  int* __restrict__ cursor) {
    int b = blockIdx.x, t = threadIdx.x;
    int base = b * CHUNK + t * 8;
    int v[8], ts = 0;
#pragma unroll
    for (int j = 0; j < 8; ++j) { int i = base + j; v[j] = (i < NB) ? cnt[i] : 0; ts += v[j]; }
    int lane = t & 63, wv = t >> 6;
    int incl = ts;
    for (int d = 1; d < 64; d <<= 1) {
        int o = __shfl_up(incl, d, 64);
        if (lane >= d) incl += o;
    }
    __shared__ int wsum[4];
    if (lane == 63) wsum[wv] = incl;
    __syncthreads();
    int wbase = 0;
    for (int w = 0; w < wv; ++w) wbase += wsum[w];
    int run = bbase[b] + wbase + incl - ts;
#pragma unroll
    for (int j = 0; j < 8; ++j) {
        int i = base + j;
        if (i < NB) { off[i] = run; cursor[i] = run; }
        run += v[j];
    }
}

// ---------------- bucket-sort edge src indices (CSR payload)
__global__ __launch_bounds__(256) void scatter_edges(const int* __restrict__ ei,
                                                     const int* __restrict__ et,
                                                     int* __restrict__ cursor,
                                                     int* __restrict__ eidx) {
    int e = blockIdx.x * 256 + threadIdx.x;
    if (e >= NE) return;
    int b = ei[NE + e] * NR + et[e];
    int pos = atomicAdd(&cursor[b], 1);
    eidx[pos] = ei[e];
}

// ---------------- layer-1 tables: tab[r][row][n], r in 0..3 (3 rels + root)
// rows: 0..7 = se @ Wseg0, 8..15 = ce @ Wseg1, 16..143 = pe @ Wseg2   (K=128 each)
__global__ __launch_bounds__(256) void tab_gemm(const float* __restrict__ se,
                                                const float* __restrict__ ce,
                                                const float* __restrict__ pe,
                                                const float* __restrict__ W1,
                                                const float* __restrict__ root1,
                                                float* __restrict__ tab) {
    int bid = blockIdx.x;              // 4*144 blocks
    int r = bid / 144, row = bid % 144;
    int t = threadIdx.x;               // output column 0..255
    const float* A; int segk;
    if (row < 8)       { A = se + row * 128;        segk = 0; }
    else if (row < 16) { A = ce + (row - 8) * 128;  segk = 128; }
    else               { A = pe + (row - 16) * 128; segk = 256; }
    const float* W = (r < 3) ? (W1 + (size_t)r * 384 * 256) : root1;
    float acc = 0.f;
    for (int k = 0; k < 128; ++k)
        acc += A[k] * W[(size_t)(segk + k) * 256 + t];
    tab[((size_t)r * 144 + row) * 256 + t] = acc;
}

// ---------------- node combo ids: combo[n] = s*1024 + c*128 + p
__global__ __launch_bounds__(256) void node_combo(const int* __restrict__ s,
                                                  const int* __restrict__ c,
                                                  const int* __restrict__ p,
                                                  int* __restrict__ combo) {
    int n = blockIdx.x * 256 + threadIdx.x;
    if (n < NN) combo[n] = (s[n] << 10) | (c[n] << 7) | p[n];
}

// ---------------- comb[r][cmb][d] = tab[r][s]+tab[r][8+c]+tab[r][16+p] (+b1 for r=3), bf16
__global__ __launch_bounds__(256) void comb_build(const float* __restrict__ tab,
                                                  const float* __restrict__ b1,
                                                  bf16* __restrict__ comb) {
    int bid = blockIdx.x;              // 4*8192
    int r = bid >> 13, cmb = bid & (NCMB - 1);
    int d = threadIdx.x;
    int si = cmb >> 10, ci = (cmb >> 7) & 7, pi = cmb & 127;
    const float* tr = tab + (size_t)r * 144 * 256;
    float v = tr[si * 256 + d] + tr[(8 + ci) * 256 + d] + tr[(16 + pi) * 256 + d];
    if (r == 3) v += b1[d];
    comb[(size_t)bid * 256 + d] = f2b(v);
}

// ---------------- fused layer 1 (64 threads = 1 wave per dst, short4/lane):
// h1[dst] = relu( sum_r mean_{src in bucket(dst,r)} comb[r][combo[src]] + comb[3][combo[dst]] )
__global__ __launch_bounds__(64) void l1_fused(const int* __restrict__ off,
                                               const int* __restrict__ eidx,
                                               const int* __restrict__ combo,
                                               const bf16* __restrict__ comb,
                                               bf16* __restrict__ h1) {
    int dst = blockIdx.x, lane = threadIdx.x;
    float ax, ay, az, aw;
    {   // root slice (b1 pre-folded)
        int cmbD = combo[dst];
        short4 rv = *(const short4*)(comb + ((size_t)(3 * NCMB + cmbD)) * 256 + lane * 4);
        ax = bs2f(rv.x); ay = bs2f(rv.y); az = bs2f(rv.z); aw = bs2f(rv.w);
    }
    for (int r = 0; r < NR; ++r) {
        int lo = off[dst * NR + r], hi = off[dst * NR + r + 1];
        if (hi <= lo) continue;                 // empty bucket contributes 0 (matches ref)
        const bf16* cr = comb + (size_t)r * NCMB * 256;
        float sx = 0.f, sy = 0.f, sz = 0.f, sw = 0.f;
        for (int j = lo; j < hi; ++j) {
            int src = eidx[j];
            int cmb = combo[src];
            short4 v = *(const short4*)(cr + (size_t)cmb * 256 + lane * 4);
            sx += bs2f(v.x); sy += bs2f(v.y); sz += bs2f(v.z); sw += bs2f(v.w);
        }
        float inv = 1.0f / (float)(hi - lo);
        ax += sx * inv; ay += sy * inv; az += sz * inv; aw += sw * inv;
    }
    short4 o;
    o.x = f2bs(fmaxf(ax, 0.f)); o.y = f2bs(fmaxf(ay, 0.f));
    o.z = f2bs(fmaxf(az, 0.f)); o.w = f2bs(fmaxf(aw, 0.f));
    *(short4*)(h1 + (size_t)dst * 256 + lane * 4) = o;
}

// ---------------- W2 -> bf16, transposed: Wt[r][n][k] = W2[r][k][n] (r=3 -> root2)
__global__ __launch_bounds__(256) void conv_w2t(const float* __restrict__ W2,
                                                const float* __restrict__ root2,
                                                bf16* __restrict__ Wt) {
    int idx = blockIdx.x * 256 + threadIdx.x;   // 4*256*256
    if (idx >= 4 * 256 * 256) return;
    int r = idx >> 16, rem = idx & 65535, n = rem >> 8, k = rem & 255;
    float v = (r < 3) ? W2[((size_t)r * 256 + k) * 256 + n] : root2[(size_t)k * 256 + n];
    Wt[idx] = f2b(v);
}

// ---------------- MFMA bf16 GEMM: C[M][256] = A[M][256] @ Bt^T  (Bt is [n][k])
// 128x128 tile, 4 waves, each wave a 64x64 quadrant = 4x4 grid of 16x16x32 MFMAs.
// root_mode: C = relu(acc + Hacc + bias) else C = acc.  bf16 out.
__global__ __launch_bounds__(256) void gemm_mfma(const bf16* __restrict__ A,
                                                 const bf16* __restrict__ Bt,
                                                 const bf16* __restrict__ Hacc,
                                                 const float* __restrict__ bias,
                                                 bf16* __restrict__ C,
                                                 int root_mode) {
    __shared__ short As[128 * 40];   // stride 40 shorts = 80 B: 16B-aligned, conflict-light
    __shared__ short Bs[128 * 40];
    const int t = threadIdx.x;
    const int wave = t >> 6, lane = t & 63;
    const int quad = lane >> 4, l16 = lane & 15;
    const int mq = (wave & 1) * 64, nq = (wave >> 1) * 64;
    const int row0 = blockIdx.y * 128, col0 = blockIdx.x * 128;
    const int sm = t >> 2;            // staging row 0..63
    const int sp = (t & 3) * 8;       // staging k-offset {0,8,16,24}

    floatx4 acc[4][4] = {};

    for (int k0 = 0; k0 < 256; k0 += 32) {
#pragma unroll
        for (int h = 0; h < 2; ++h) {
            int m = sm + h * 64;
            int gm = row0 + m;
            short8 av = {};
            if (gm < NN) av = *(const short8*)(A + (size_t)gm * 256 + k0 + sp);
            *(short8*)&As[m * 40 + sp] = av;
            short8 bv = *(const short8*)(Bt + (size_t)(col0 + m) * 256 + k0 + sp);
            *(short8*)&Bs[m * 40 + sp] = bv;
        }
        __syncthreads();
        short8 af[4], bfr[4];
#pragma unroll
        for (int i = 0; i < 4; ++i)
            af[i] = *(const short8*)&As[(mq + i * 16 + l16) * 40 + quad * 8];
#pragma unroll
        for (int i = 0; i < 4; ++i)
            bfr[i] = *(const short8*)&Bs[(nq + i * 16 + l16) * 40 + quad * 8];
#pragma unroll
        for (int mi = 0; mi < 4; ++mi)
#pragma unroll
            for (int ni = 0; ni < 4; ++ni)
                acc[mi][ni] = __builtin_amdgcn_mfma_f32_16x16x32_bf16(
                    af[mi], bfr[ni], acc[mi][ni], 0, 0, 0);
        __syncthreads();
    }

    // C/D layout: col = lane&15, row = quad*4 + reg   [m89/m91-verified]
#pragma unroll
    for (int mi = 0; mi < 4; ++mi) {
#pragma unroll
        for (int ni = 0; ni < 4; ++ni) {
            int n = col0 + nq + ni * 16 + l16;
#pragma unroll
            for (int i = 0; i < 4; ++i) {
                int gm = row0 + mq + mi * 16 + quad * 4 + i;
                if (gm < NN) {
                    float v = acc[mi][ni][i];
                    if (root_mode) {
                        v += b2f(Hacc[(size_t)gm * 256 + n]) + bias[n];
                        v = fmaxf(v, 0.f);
                    }
                    C[(size_t)gm * 256 + n] = f2b(v);
                }
            }
        }
    }
}

// ---------------- segmented mean per (dst, r): H[dst] += mean_{src in bucket} Y[src]
// 64 threads (1 wave), short4/lane = full 512 B row per wave-instruction.
__global__ __launch_bounds__(64) void agg_mean(const int* __restrict__ off,
                                               const int* __restrict__ eidx,
                                               const bf16* __restrict__ Y,
                                               bf16* __restrict__ H, int r) {
    int dst = blockIdx.x, lane = threadIdx.x;
    int b = dst * NR + r;
    int lo = off[b], hi = off[b + 1];
    if (lo == hi) return;
    float sx = 0.f, sy = 0.f, sz = 0.f, sw = 0.f;
    for (int j = lo; j < hi; ++j) {
        int src = eidx[j];
        short4 v = *(const short4*)(Y + (size_t)src * 256 + lane * 4);
        sx += bs2f(v.x); sy += bs2f(v.y); sz += bs2f(v.z); sw += bs2f(v.w);
    }
    float inv = 1.0f / (float)(hi - lo);
    size_t o = (size_t)dst * 256 + lane * 4;
    short4 hv = *(short4*)(H + o);
    hv.x = f2bs(bs2f(hv.x) + sx * inv);
    hv.y = f2bs(bs2f(hv.y) + sy * inv);
    hv.z = f2bs(bs2f(hv.z) + sz * inv);
    hv.w = f2bs(bs2f(hv.w) + sw * inv);
    *(short4*)(H + o) = hv;
}

// ---------------- pooling via run-length reduction (batch is SORTED):
// block covers 64 consecutive nodes; flush one atomic per graph-run per thread.
#define PN 64
__global__ __launch_bounds__(256) void pool_rle(const int* __restrict__ batch,
                                                const bf16* __restrict__ H,
                                                float* __restrict__ pool,
                                                float* __restrict__ gcnt) {
    int t = threadIdx.x;               // feature dim
    int n0 = blockIdx.x * PN;
    int nend = n0 + PN; if (nend > NN) nend = NN;
    int curg = batch[n0];
    float acc = 0.f, cnt = 0.f;
    for (int n = n0; n < nend; ++n) {
        int g = batch[n];              // wave-uniform
        if (g != curg) {
            atomicAdd(&pool[(size_t)curg * 256 + t], acc);
            if (t == 0) atomicAdd(&gcnt[curg], cnt);
            acc = 0.f; cnt = 0.f; curg = g;
        }
        acc += b2f(H[(size_t)n * 256 + t]);
        cnt += 1.f;
    }
    atomicAdd(&pool[(size_t)curg * 256 + t], acc);
    if (t == 0) atomicAdd(&gcnt[curg], cnt);
}

// ---------------- head: out[g][c] = (pool[g]/cnt[g]) @ lin_w + lin_b  (f32 out)
__global__ __launch_bounds__(256) void final_head(const float* __restrict__ pool,
                                                  const float* __restrict__ gcnt,
                                                  const float* __restrict__ lin_w,
                                                  const float* __restrict__ lin_b,
                                                  float* __restrict__ out) {
    __shared__ float sm[256];
    int g = blockIdx.x, t = threadIdx.x;
    float inv = 1.0f / fmaxf(gcnt[g], 1.0f);
    sm[t] = pool[(size_t)g * 256 + t] * inv;
    __syncthreads();
    if (t < NCLS) {
        float s = lin_b[t];
        for (int d = 0; d < 256; ++d) s += sm[d] * lin_w[d * NCLS + t];
        out[g * NCLS + t] = s;
    }
}

extern "C" void kernel_launch(void* const* d_in, const int* in_sizes, int n_in,
                              void* d_out, int out_size, void* d_ws, size_t ws_size,
                              hipStream_t stream) {
    const int*   s_idx = (const int*)d_in[0];
    const int*   c_idx = (const int*)d_in[1];
    const int*   p_idx = (const int*)d_in[2];
    const int*   ei    = (const int*)d_in[3];   // (2, NE)
    const int*   et    = (const int*)d_in[4];
    const int*   batch = (const int*)d_in[5];
    const float* se    = (const float*)d_in[6];
    const float* ce    = (const float*)d_in[7];
    const float* pe    = (const float*)d_in[8];
    const float* W1    = (const float*)d_in[9];   // (3, 384, 256)
    const float* root1 = (const float*)d_in[10];  // (384, 256)
    const float* b1    = (const float*)d_in[11];
    const float* W2    = (const float*)d_in[12];  // (3, 256, 256)
    const float* root2 = (const float*)d_in[13];  // (256, 256)
    const float* b2    = (const float*)d_in[14];
    const float* lin_w = (const float*)d_in[15];
    const float* lin_b = (const float*)d_in[16];
    float* out = (float*)d_out;

    // ---- workspace carve-up (~102 MB; 16B-aligned)
    char* w = (char*)d_ws;
    size_t o = 0;
    auto alloc = [&](size_t bytes) -> void* {
        o = (o + 15) & ~(size_t)15;
        void* ptr = w + o;
        o += bytes;
        return ptr;
    };
    bf16*  Yr     = (bf16*) alloc((size_t)NN * 256 * 2);
    bf16*  h1     = (bf16*) alloc((size_t)NN * 256 * 2);
    bf16*  h2     = (bf16*) alloc((size_t)NN * 256 * 2);
    bf16*  comb   = (bf16*) alloc((size_t)4 * NCMB * 256 * 2);
    int*   combo  = (int*)  alloc((size_t)NN * 4);
    int*   eidx   = (int*)  alloc((size_t)NE * 4);
    int*   cnt    = (int*)  alloc((size_t)NB * 4);
    int*   off    = (int*)  alloc((size_t)(NB + 1) * 4);
    int*   cursor = (int*)  alloc((size_t)NB * 4);
    int*   bsum   = (int*)  alloc((size_t)NBLK * 4);
    int*   bbase  = (int*)  alloc((size_t)NBLK * 4);
    float* tab    = (float*)alloc((size_t)4 * 144 * 256 * 4);
    bf16*  W2t    = (bf16*) alloc((size_t)4 * 256 * 256 * 2);
    float* pool   = (float*)alloc((size_t)NG * 256 * 4);
    float* gcnt   = (float*)alloc((size_t)NG * 4);
    (void)ws_size;

    const long HW = (long)NN * 128;     // h buffer in u32 words

    // ---- CSR build
    zero_u32<<<(NB + 255) / 256, 256, 0, stream>>>((unsigned*)cnt, NB);
    count_edges<<<(NE + 255) / 256, 256, 0, stream>>>(ei, et, cnt);
    scan_block_sums<<<NBLK, 256, 0, stream>>>(cnt, bsum);
    scan_base<<<1, 64, 0, stream>>>(bsum, bbase, off);
    scan_write<<<NBLK, 256, 0, stream>>>(cnt, bbase, off, cursor);
    scatter_edges<<<(NE + 255) / 256, 256, 0, stream>>>(ei, et, cursor, eidx);

    // ---- weight/table prep
    tab_gemm<<<4 * 144, 256, 0, stream>>>(se, ce, pe, W1, root1, tab);
    node_combo<<<(NN + 255) / 256, 256, 0, stream>>>(s_idx, c_idx, p_idx, combo);
    comb_build<<<4 * NCMB, 256, 0, stream>>>(tab, b1, comb);
    conv_w2t<<<(4 * 256 * 256 + 255) / 256, 256, 0, stream>>>(W2, root2, W2t);

    // ---- layer 1: fully fused combo-table gather
    l1_fused<<<NN, 64, 0, stream>>>(off, eidx, combo, comb, h1);

    // ---- layer 2: MFMA GEMM per relation + CSR mean-agg; root GEMM fuses epilogue
    zero_u32<<<(int)((HW + 255) / 256), 256, 0, stream>>>((unsigned*)h2, HW);
    dim3 ggrid(2, (NN + 127) / 128);
    for (int r = 0; r < NR; ++r) {
        gemm_mfma<<<ggrid, 256, 0, stream>>>(h1, W2t + (size_t)r * 256 * 256, h2, b2, Yr, 0);
        agg_mean<<<NN, 64, 0, stream>>>(off, eidx, Yr, h2, r);
    }
    gemm_mfma<<<ggrid, 256, 0, stream>>>(h1, W2t + (size_t)3 * 256 * 256, h2, b2, h2, 1);

    // ---- pool + head
    zero_u32<<<(NG * 256 + NG + 255) / 256, 256, 0, stream>>>((unsigned*)pool, NG * 256 + NG);
    pool_rle<<<(NN + PN - 1) / PN, 256, 0, stream>>>(batch, h2, pool, gcnt);
    final_head<<<NG, 256, 0, stream>>>(pool, gcnt, lin_w, lin_b, out);
}

// Round 6
// 452.744 us; speedup vs baseline: 5.3312x; 1.1889x over previous
//
#include <hip/hip_runtime.h>
#include <hip/hip_bf16.h>

#define NN 50000          // nodes
#define NE 800000         // edges
#define NR 3              // relations
#define NG 500            // graphs
#define NB (NN * NR)      // (dst, rel) buckets = 150000
#define NCLS 10
#define NCMB 8192         // 8 shapes * 8 colors * 128 positions
#define CHUNK 2048        // scan elements per block
#define NBLK ((NB + CHUNK - 1) / CHUNK)   // 74

typedef __hip_bfloat16 bf16;
typedef __attribute__((ext_vector_type(8))) short short8;   // bf16x8 MFMA frag
typedef __attribute__((ext_vector_type(4))) float floatx4;  // MFMA accumulator

static __device__ __forceinline__ float b2f(bf16 x) { return __bfloat162float(x); }
static __device__ __forceinline__ bf16  f2b(float x) { return __float2bfloat16(x); }
static __device__ __forceinline__ float bs2f(short x) {
    return __bfloat162float(*reinterpret_cast<const bf16*>(&x));
}
static __device__ __forceinline__ short f2bs(float x) {
    bf16 b = __float2bfloat16(x);
    return *reinterpret_cast<const short*>(&b);
}

// ---------------- zero words (graph-capture-safe)
__global__ __launch_bounds__(256) void zero_u32(unsigned* __restrict__ p, long n) {
    long i = (long)blockIdx.x * 256 + threadIdx.x;
    if (i < n) p[i] = 0u;
}

// ---------------- per-(dst,rel) edge counts
__global__ __launch_bounds__(256) void count_edges(const int* __restrict__ ei,
                                                   const int* __restrict__ et,
                                                   int* __restrict__ cnt) {
    int e = blockIdx.x * 256 + threadIdx.x;
    if (e >= NE) return;
    atomicAdd(&cnt[ei[NE + e] * NR + et[e]], 1);
}

// ---------------- counting-sort scan, phase A: per-block (2048-elem) totals
__global__ __launch_bounds__(256) void scan_block_sums(const int* __restrict__ cnt,
                                                       int* __restrict__ bsum) {
    __shared__ int sm[256];
    int b = blockIdx.x, t = threadIdx.x;
    int base = b * CHUNK + t * 8, s = 0;
#pragma unroll
    for (int j = 0; j < 8; ++j) { int i = base + j; if (i < NB) s += cnt[i]; }
    sm[t] = s; __syncthreads();
    for (int st = 128; st; st >>= 1) { if (t < st) sm[t] += sm[t + st]; __syncthreads(); }
    if (!t) bsum[b] = sm[0];
}

// ---------------- phase B: exclusive scan of the 74 block sums
__global__ void scan_base(const int* __restrict__ bsum, int* __restrict__ bbase,
                          int* __restrict__ off) {
    if (threadIdx.x == 0 && blockIdx.x == 0) {
        int run = 0;
        for (int i = 0; i < NBLK; ++i) { bbase[i] = run; run += bsum[i]; }
        off[NB] = run;   // == NE
    }
}

// ---------------- phase C: in-block exclusive scan + base -> off[], cursor[]
__global__ __launch_bounds__(256) void scan_write(const int* __restrict__ cnt,
                                                  const int* __restrict__ bbase,
                                                  int* __restrict__ off,
                                                  int* __restrict__ cursor) {
    int b = blockIdx.x, t = threadIdx.x;
    int base = b * CHUNK + t * 8;
    int v[8], ts = 0;
#pragma unroll
    for (int j = 0; j < 8; ++j) { int i = base + j; v[j] = (i < NB) ? cnt[i] : 0; ts += v[j]; }
    int lane = t & 63, wv = t >> 6;
    int incl = ts;
    for (int d = 1; d < 64; d <<= 1) {
        int o = __shfl_up(incl, d, 64);
        if (lane >= d) incl += o;
    }
    __shared__ int wsum[4];
    if (lane == 63) wsum[wv] = incl;
    __syncthreads();
    int wbase = 0;
    for (int w = 0; w < wv; ++w) wbase += wsum[w];
    int run = bbase[b] + wbase + incl - ts;
#pragma unroll
    for (int j = 0; j < 8; ++j) {
        int i = base + j;
        if (i < NB) { off[i] = run; cursor[i] = run; }
        run += v[j];
    }
}

// ---------------- bucket-sort edge src indices (CSR payload)
__global__ __launch_bounds__(256) void scatter_edges(const int* __restrict__ ei,
                                                     const int* __restrict__ et,
                                                     int* __restrict__ cursor,
                                                     int* __restrict__ eidx) {
    int e = blockIdx.x * 256 + threadIdx.x;
    if (e >= NE) return;
    int b = ei[NE + e] * NR + et[e];
    int pos = atomicAdd(&cursor[b], 1);
    eidx[pos] = ei[e];
}

// ---------------- layer-1 tables: tab[r][row][n], r in 0..3 (3 rels + root)
__global__ __launch_bounds__(256) void tab_gemm(const float* __restrict__ se,
                                                const float* __restrict__ ce,
                                                const float* __restrict__ pe,
                                                const float* __restrict__ W1,
                                                const float* __restrict__ root1,
                                                float* __restrict__ tab) {
    int bid = blockIdx.x;              // 4*144 blocks
    int r = bid / 144, row = bid % 144;
    int t = threadIdx.x;               // output column 0..255
    const float* A; int segk;
    if (row < 8)       { A = se + row * 128;        segk = 0; }
    else if (row < 16) { A = ce + (row - 8) * 128;  segk = 128; }
    else               { A = pe + (row - 16) * 128; segk = 256; }
    const float* W = (r < 3) ? (W1 + (size_t)r * 384 * 256) : root1;
    float acc = 0.f;
    for (int k = 0; k < 128; ++k)
        acc += A[k] * W[(size_t)(segk + k) * 256 + t];
    tab[((size_t)r * 144 + row) * 256 + t] = acc;
}

// ---------------- node combo ids: combo[n] = s*1024 + c*128 + p
__global__ __launch_bounds__(256) void node_combo(const int* __restrict__ s,
                                                  const int* __restrict__ c,
                                                  const int* __restrict__ p,
                                                  int* __restrict__ combo) {
    int n = blockIdx.x * 256 + threadIdx.x;
    if (n < NN) combo[n] = (s[n] << 10) | (c[n] << 7) | p[n];
}

// ---------------- comb[r][cmb][d] = tab[r][s]+tab[r][8+c]+tab[r][16+p] (+b1 for r=3), bf16
__global__ __launch_bounds__(256) void comb_build(const float* __restrict__ tab,
                                                  const float* __restrict__ b1,
                                                  bf16* __restrict__ comb) {
    int bid = blockIdx.x;              // 4*8192
    int r = bid >> 13, cmb = bid & (NCMB - 1);
    int d = threadIdx.x;
    int si = cmb >> 10, ci = (cmb >> 7) & 7, pi = cmb & 127;
    const float* tr = tab + (size_t)r * 144 * 256;
    float v = tr[si * 256 + d] + tr[(8 + ci) * 256 + d] + tr[(16 + pi) * 256 + d];
    if (r == 3) v += b1[d];
    comb[(size_t)bid * 256 + d] = f2b(v);
}

// ---------------- fused layer 1 (1 wave per dst, short4/lane, 4-deep MLP gather)
__global__ __launch_bounds__(64) void l1_fused(const int* __restrict__ off,
                                               const int* __restrict__ eidx,
                                               const int* __restrict__ combo,
                                               const bf16* __restrict__ comb,
                                               bf16* __restrict__ h1) {
    int dst = blockIdx.x, li4 = threadIdx.x * 4;
    float ax, ay, az, aw;
    {   // root slice (b1 pre-folded)
        int cmbD = combo[dst];
        short4 rv = *(const short4*)(comb + ((size_t)(3 * NCMB) + cmbD) * 256 + li4);
        ax = bs2f(rv.x); ay = bs2f(rv.y); az = bs2f(rv.z); aw = bs2f(rv.w);
    }
    for (int r = 0; r < NR; ++r) {
        int lo = off[dst * NR + r], hi = off[dst * NR + r + 1];
        if (hi <= lo) continue;                 // empty bucket contributes 0 (matches ref)
        const bf16* cr = comb + (size_t)r * NCMB * 256;
        float sx = 0.f, sy = 0.f, sz = 0.f, sw = 0.f;
        int j = lo;
        for (; j + 4 <= hi; j += 4) {           // 4 independent row loads in flight
            int s0 = eidx[j], s1 = eidx[j + 1], s2 = eidx[j + 2], s3 = eidx[j + 3];
            int c0 = combo[s0], c1 = combo[s1], c2 = combo[s2], c3 = combo[s3];
            short4 v0 = *(const short4*)(cr + (size_t)c0 * 256 + li4);
            short4 v1 = *(const short4*)(cr + (size_t)c1 * 256 + li4);
            short4 v2 = *(const short4*)(cr + (size_t)c2 * 256 + li4);
            short4 v3 = *(const short4*)(cr + (size_t)c3 * 256 + li4);
            sx += bs2f(v0.x) + bs2f(v1.x) + bs2f(v2.x) + bs2f(v3.x);
            sy += bs2f(v0.y) + bs2f(v1.y) + bs2f(v2.y) + bs2f(v3.y);
            sz += bs2f(v0.z) + bs2f(v1.z) + bs2f(v2.z) + bs2f(v3.z);
            sw += bs2f(v0.w) + bs2f(v1.w) + bs2f(v2.w) + bs2f(v3.w);
        }
        for (; j < hi; ++j) {
            int cc = combo[eidx[j]];
            short4 v = *(const short4*)(cr + (size_t)cc * 256 + li4);
            sx += bs2f(v.x); sy += bs2f(v.y); sz += bs2f(v.z); sw += bs2f(v.w);
        }
        float inv = 1.0f / (float)(hi - lo);
        ax += sx * inv; ay += sy * inv; az += sz * inv; aw += sw * inv;
    }
    short4 o;
    o.x = f2bs(fmaxf(ax, 0.f)); o.y = f2bs(fmaxf(ay, 0.f));
    o.z = f2bs(fmaxf(az, 0.f)); o.w = f2bs(fmaxf(aw, 0.f));
    *(short4*)(h1 + (size_t)dst * 256 + li4) = o;
}

// ---------------- W2 -> bf16, transposed: Wt[n_glob][k]; n_glob = r*256+n (r=3 -> root2)
__global__ __launch_bounds__(256) void conv_w2t(const float* __restrict__ W2,
                                                const float* __restrict__ root2,
                                                bf16* __restrict__ Wt) {
    int idx = blockIdx.x * 256 + threadIdx.x;   // 4*256*256
    if (idx >= 4 * 256 * 256) return;
    int r = idx >> 16, rem = idx & 65535, n = rem >> 8, k = rem & 255;
    float v = (r < 3) ? W2[((size_t)r * 256 + k) * 256 + n] : root2[(size_t)k * 256 + n];
    Wt[idx] = f2b(v);
}

// ---------------- MFMA bf16 GEMM: C[M][cstride] tile = A[M][256] @ Bt^T  (Bt is [n][k])
// 128x128 tile, 4 waves, each a 64x64 quadrant = 4x4 grid of 16x16x32 MFMAs.
// root_mode: C = relu(acc + Hacc + bias) (narrow path only).
__global__ __launch_bounds__(256) void gemm_mfma(const bf16* __restrict__ A,
                                                 const bf16* __restrict__ Bt,
                                                 const bf16* __restrict__ Hacc,
                                                 const float* __restrict__ bias,
                                                 bf16* __restrict__ C,
                                                 int cstride, int root_mode) {
    __shared__ short As[128 * 40];   // stride 40 shorts = 80 B (16B-aligned rows)
    __shared__ short Bs[128 * 40];
    const int t = threadIdx.x;
    const int wave = t >> 6, lane = t & 63;
    const int quad = lane >> 4, l16 = lane & 15;
    const int mq = (wave & 1) * 64, nq = (wave >> 1) * 64;
    const int row0 = blockIdx.y * 128, col0 = blockIdx.x * 128;
    const int sm = t >> 2;            // staging row 0..63
    const int sp = (t & 3) * 8;       // staging k-offset {0,8,16,24}

    floatx4 acc[4][4] = {};

    for (int k0 = 0; k0 < 256; k0 += 32) {
#pragma unroll
        for (int h = 0; h < 2; ++h) {
            int m = sm + h * 64;
            int gm = row0 + m;
            short8 av = {};
            if (gm < NN) av = *(const short8*)(A + (size_t)gm * 256 + k0 + sp);
            *(short8*)&As[m * 40 + sp] = av;
            short8 bv = *(const short8*)(Bt + (size_t)(col0 + m) * 256 + k0 + sp);
            *(short8*)&Bs[m * 40 + sp] = bv;
        }
        __syncthreads();
        short8 af[4], bfr[4];
#pragma unroll
        for (int i = 0; i < 4; ++i)
            af[i] = *(const short8*)&As[(mq + i * 16 + l16) * 40 + quad * 8];
#pragma unroll
        for (int i = 0; i < 4; ++i)
            bfr[i] = *(const short8*)&Bs[(nq + i * 16 + l16) * 40 + quad * 8];
#pragma unroll
        for (int mi = 0; mi < 4; ++mi)
#pragma unroll
            for (int ni = 0; ni < 4; ++ni)
                acc[mi][ni] = __builtin_amdgcn_mfma_f32_16x16x32_bf16(
                    af[mi], bfr[ni], acc[mi][ni], 0, 0, 0);
        __syncthreads();
    }

    // C/D layout: col = lane&15, row = quad*4 + reg   [m89/m91-verified]
#pragma unroll
    for (int mi = 0; mi < 4; ++mi) {
#pragma unroll
        for (int ni = 0; ni < 4; ++ni) {
            int n = col0 + nq + ni * 16 + l16;
#pragma unroll
            for (int i = 0; i < 4; ++i) {
                int gm = row0 + mq + mi * 16 + quad * 4 + i;
                if (gm < NN) {
                    float v = acc[mi][ni][i];
                    if (root_mode) {
                        v += b2f(Hacc[(size_t)gm * 256 + n]) + bias[n];
                        v = fmaxf(v, 0.f);
                    }
                    C[(size_t)gm * cstride + n] = f2b(v);
                }
            }
        }
    }
}

// ---------------- WIDE: fused layer-2 epilogue: h2[dst] = relu( sum_r mean Y[src, r*256:]
//                  + Y[dst, 768:1024] + b2 ).  1 wave/dst, 4-deep MLP gather.
__global__ __launch_bounds__(64) void l2_fused(const int* __restrict__ off,
                                               const int* __restrict__ eidx,
                                               const bf16* __restrict__ Y,
                                               const float* __restrict__ bias,
                                               bf16* __restrict__ h2) {
    int dst = blockIdx.x, li4 = threadIdx.x * 4;
    float4 bb = *(const float4*)(bias + li4);
    short4 rv = *(const short4*)(Y + (size_t)dst * 1024 + 768 + li4);
    float ax = bs2f(rv.x) + bb.x, ay = bs2f(rv.y) + bb.y;
    float az = bs2f(rv.z) + bb.z, aw = bs2f(rv.w) + bb.w;
    for (int r = 0; r < NR; ++r) {
        int lo = off[dst * NR + r], hi = off[dst * NR + r + 1];
        if (hi <= lo) continue;
        const bf16* yr = Y + (size_t)r * 256;
        float sx = 0.f, sy = 0.f, sz = 0.f, sw = 0.f;
        int j = lo;
        for (; j + 4 <= hi; j += 4) {
            int s0 = eidx[j], s1 = eidx[j + 1], s2 = eidx[j + 2], s3 = eidx[j + 3];
            short4 v0 = *(const short4*)(yr + (size_t)s0 * 1024 + li4);
            short4 v1 = *(const short4*)(yr + (size_t)s1 * 1024 + li4);
            short4 v2 = *(const short4*)(yr + (size_t)s2 * 1024 + li4);
            short4 v3 = *(const short4*)(yr + (size_t)s3 * 1024 + li4);
            sx += bs2f(v0.x) + bs2f(v1.x) + bs2f(v2.x) + bs2f(v3.x);
            sy += bs2f(v0.y) + bs2f(v1.y) + bs2f(v2.y) + bs2f(v3.y);
            sz += bs2f(v0.z) + bs2f(v1.z) + bs2f(v2.z) + bs2f(v3.z);
            sw += bs2f(v0.w) + bs2f(v1.w) + bs2f(v2.w) + bs2f(v3.w);
        }
        for (; j < hi; ++j) {
            short4 v = *(const short4*)(yr + (size_t)eidx[j] * 1024 + li4);
            sx += bs2f(v.x); sy += bs2f(v.y); sz += bs2f(v.z); sw += bs2f(v.w);
        }
        float inv = 1.0f / (float)(hi - lo);
        ax += sx * inv; ay += sy * inv; az += sz * inv; aw += sw * inv;
    }
    short4 o;
    o.x = f2bs(fmaxf(ax, 0.f)); o.y = f2bs(fmaxf(ay, 0.f));
    o.z = f2bs(fmaxf(az, 0.f)); o.w = f2bs(fmaxf(aw, 0.f));
    *(short4*)(h2 + (size_t)dst * 256 + li4) = o;
}

// ---------------- NARROW fallback: segmented mean per (dst,r) from Yr, 4-deep MLP
__global__ __launch_bounds__(64) void agg_mean(const int* __restrict__ off,
                                               const int* __restrict__ eidx,
                                               const bf16* __restrict__ Y,
                                               bf16* __restrict__ H, int r) {
    int dst = blockIdx.x, li4 = threadIdx.x * 4;
    int b = dst * NR + r;
    int lo = off[b], hi = off[b + 1];
    if (lo == hi) return;
    float sx = 0.f, sy = 0.f, sz = 0.f, sw = 0.f;
    int j = lo;
    for (; j + 4 <= hi; j += 4) {
        int s0 = eidx[j], s1 = eidx[j + 1], s2 = eidx[j + 2], s3 = eidx[j + 3];
        short4 v0 = *(const short4*)(Y + (size_t)s0 * 256 + li4);
        short4 v1 = *(const short4*)(Y + (size_t)s1 * 256 + li4);
        short4 v2 = *(const short4*)(Y + (size_t)s2 * 256 + li4);
        short4 v3 = *(const short4*)(Y + (size_t)s3 * 256 + li4);
        sx += bs2f(v0.x) + bs2f(v1.x) + bs2f(v2.x) + bs2f(v3.x);
        sy += bs2f(v0.y) + bs2f(v1.y) + bs2f(v2.y) + bs2f(v3.y);
        sz += bs2f(v0.z) + bs2f(v1.z) + bs2f(v2.z) + bs2f(v3.z);
        sw += bs2f(v0.w) + bs2f(v1.w) + bs2f(v2.w) + bs2f(v3.w);
    }
    for (; j < hi; ++j) {
        short4 v = *(const short4*)(Y + (size_t)eidx[j] * 256 + li4);
        sx += bs2f(v.x); sy += bs2f(v.y); sz += bs2f(v.z); sw += bs2f(v.w);
    }
    float inv = 1.0f / (float)(hi - lo);
    size_t o = (size_t)dst * 256 + li4;
    short4 hv = *(short4*)(H + o);
    hv.x = f2bs(bs2f(hv.x) + sx * inv);
    hv.y = f2bs(bs2f(hv.y) + sy * inv);
    hv.z = f2bs(bs2f(hv.z) + sz * inv);
    hv.w = f2bs(bs2f(hv.w) + sw * inv);
    *(short4*)(H + o) = hv;
}

// ---------------- pooling via run-length reduction (batch is SORTED)
#define PN 64
__global__ __launch_bounds__(256) void pool_rle(const int* __restrict__ batch,
                                                const bf16* __restrict__ H,
                                                float* __restrict__ pool,
                                                float* __restrict__ gcnt) {
    int t = threadIdx.x;               // feature dim
    int n0 = blockIdx.x * PN;
    int nend = n0 + PN; if (nend > NN) nend = NN;
    int curg = batch[n0];
    float acc = 0.f, cnt = 0.f;
    for (int n = n0; n < nend; ++n) {
        int g = batch[n];              // wave-uniform
        if (g != curg) {
            atomicAdd(&pool[(size_t)curg * 256 + t], acc);
            if (t == 0) atomicAdd(&gcnt[curg], cnt);
            acc = 0.f; cnt = 0.f; curg = g;
        }
        acc += b2f(H[(size_t)n * 256 + t]);
        cnt += 1.f;
    }
    atomicAdd(&pool[(size_t)curg * 256 + t], acc);
    if (t == 0) atomicAdd(&gcnt[curg], cnt);
}

// ---------------- head: out[g][c] = (pool[g]/cnt[g]) @ lin_w + lin_b  (f32 out)
__global__ __launch_bounds__(256) void final_head(const float* __restrict__ pool,
                                                  const float* __restrict__ gcnt,
                                                  const float* __restrict__ lin_w,
                                                  const float* __restrict__ lin_b,
                                                  float* __restrict__ out) {
    __shared__ float sm[256];
    int g = blockIdx.x, t = threadIdx.x;
    float inv = 1.0f / fmaxf(gcnt[g], 1.0f);
    sm[t] = pool[(size_t)g * 256 + t] * inv;
    __syncthreads();
    if (t < NCLS) {
        float s = lin_b[t];
        for (int d = 0; d < 256; ++d) s += sm[d] * lin_w[d * NCLS + t];
        out[g * NCLS + t] = s;
    }
}

extern "C" void kernel_launch(void* const* d_in, const int* in_sizes, int n_in,
                              void* d_out, int out_size, void* d_ws, size_t ws_size,
                              hipStream_t stream) {
    const int*   s_idx = (const int*)d_in[0];
    const int*   c_idx = (const int*)d_in[1];
    const int*   p_idx = (const int*)d_in[2];
    const int*   ei    = (const int*)d_in[3];   // (2, NE)
    const int*   et    = (const int*)d_in[4];
    const int*   batch = (const int*)d_in[5];
    const float* se    = (const float*)d_in[6];
    const float* ce    = (const float*)d_in[7];
    const float* pe    = (const float*)d_in[8];
    const float* W1    = (const float*)d_in[9];   // (3, 384, 256)
    const float* root1 = (const float*)d_in[10];  // (384, 256)
    const float* b1    = (const float*)d_in[11];
    const float* W2    = (const float*)d_in[12];  // (3, 256, 256)
    const float* root2 = (const float*)d_in[13];  // (256, 256)
    const float* b2    = (const float*)d_in[14];
    const float* lin_w = (const float*)d_in[15];
    const float* lin_b = (const float*)d_in[16];
    float* out = (float*)d_out;

    // wide path needs Y[NN x 1024] bf16 (102.4 MB) -> total ~178 MB; guard on ws_size.
    const bool wide = ws_size >= (size_t)190 * 1024 * 1024;

    char* w = (char*)d_ws;
    size_t o = 0;
    auto alloc = [&](size_t bytes) -> void* {
        o = (o + 15) & ~(size_t)15;
        void* ptr = w + o;
        o += bytes;
        return ptr;
    };
    bf16*  Ybuf   = (bf16*) alloc((size_t)NN * (wide ? 1024 : 256) * 2);
    bf16*  h1     = (bf16*) alloc((size_t)NN * 256 * 2);
    bf16*  h2     = (bf16*) alloc((size_t)NN * 256 * 2);
    bf16*  comb   = (bf16*) alloc((size_t)4 * NCMB * 256 * 2);
    int*   combo  = (int*)  alloc((size_t)NN * 4);
    int*   eidx   = (int*)  alloc((size_t)NE * 4);
    int*   cnt    = (int*)  alloc((size_t)NB * 4);
    int*   off    = (int*)  alloc((size_t)(NB + 1) * 4);
    int*   cursor = (int*)  alloc((size_t)NB * 4);
    int*   bsum   = (int*)  alloc((size_t)NBLK * 4);
    int*   bbase  = (int*)  alloc((size_t)NBLK * 4);
    float* tab    = (float*)alloc((size_t)4 * 144 * 256 * 4);
    bf16*  W2t    = (bf16*) alloc((size_t)4 * 256 * 256 * 2);
    float* pool   = (float*)alloc((size_t)NG * 256 * 4);
    float* gcnt   = (float*)alloc((size_t)NG * 4);

    const long HW = (long)NN * 128;     // h buffer in u32 words

    // ---- CSR build
    zero_u32<<<(NB + 255) / 256, 256, 0, stream>>>((unsigned*)cnt, NB);
    count_edges<<<(NE + 255) / 256, 256, 0, stream>>>(ei, et, cnt);
    scan_block_sums<<<NBLK, 256, 0, stream>>>(cnt, bsum);
    scan_base<<<1, 64, 0, stream>>>(bsum, bbase, off);
    scan_write<<<NBLK, 256, 0, stream>>>(cnt, bbase, off, cursor);
    scatter_edges<<<(NE + 255) / 256, 256, 0, stream>>>(ei, et, cursor, eidx);

    // ---- weight/table prep
    tab_gemm<<<4 * 144, 256, 0, stream>>>(se, ce, pe, W1, root1, tab);
    node_combo<<<(NN + 255) / 256, 256, 0, stream>>>(s_idx, c_idx, p_idx, combo);
    comb_build<<<4 * NCMB, 256, 0, stream>>>(tab, b1, comb);
    conv_w2t<<<(4 * 256 * 256 + 255) / 256, 256, 0, stream>>>(W2, root2, W2t);

    // ---- layer 1: fully fused combo-table gather
    l1_fused<<<NN, 64, 0, stream>>>(off, eidx, combo, comb, h1);

    // ---- layer 2
    if (wide) {
        // one GEMM: Y[NN x 1024] = h1 @ [W2_0|W2_1|W2_2|root2]^T, then one fused epilogue
        dim3 g8(8, (NN + 127) / 128);
        gemm_mfma<<<g8, 256, 0, stream>>>(h1, W2t, nullptr, nullptr, Ybuf, 1024, 0);
        l2_fused<<<NN, 64, 0, stream>>>(off, eidx, Ybuf, b2, h2);
    } else {
        zero_u32<<<(int)((HW + 255) / 256), 256, 0, stream>>>((unsigned*)h2, HW);
        dim3 g2(2, (NN + 127) / 128);
        for (int r = 0; r < NR; ++r) {
            gemm_mfma<<<g2, 256, 0, stream>>>(h1, W2t + (size_t)r * 256 * 256,
                                              nullptr, nullptr, Ybuf, 256, 0);
            agg_mean<<<NN, 64, 0, stream>>>(off, eidx, Ybuf, h2, r);
        }
        gemm_mfma<<<g2, 256, 0, stream>>>(h1, W2t + (size_t)3 * 256 * 256, h2, b2, h2, 256, 1);
    }

    // ---- pool + head
    zero_u32<<<(NG * 256 + NG + 255) / 256, 256, 0, stream>>>((unsigned*)pool, NG * 256 + NG);
    pool_rle<<<(NN + PN - 1) / PN, 256, 0, stream>>>(batch, h2, pool, gcnt);
    final_head<<<NG, 256, 0, stream>>>(pool, gcnt, lin_w, lin_b, out);
}